// Round 10
// baseline (27.935 us; speedup 1.0000x reference)
//
#include <hip/hip_runtime.h>

// HybridQAE: analytic encoder (Heisenberg-reduced: RZ drops out, CNOT+RY ->
// products of per-qubit cos/sin) + MFMA MLP 4->16->32->16 (16x16x32_f16,
// fp32 accum). Wave = 64 samples (lane = sample); inter-layer transposes via
// ds_bpermute (__shfl): no LDS scratch, no barriers, no bank conflicts.
// Grid-stride 4 tiles/block with next-tile prefetch: iteration k+1's loads
// issue before iteration k's compute, hiding HBM latency under the MLP.

typedef _Float16 f16x8 __attribute__((ext_vector_type(8)));
typedef _Float16 f16x4 __attribute__((ext_vector_type(4)));
typedef float    f32x4 __attribute__((ext_vector_type(4)));
typedef int      i32x4 __attribute__((ext_vector_type(4)));

#define TPB 4   // tiles (of 256 samples) per block

__device__ __forceinline__ int2 pack4(float a, float b, float c, float d) {
    f16x4 v = { (_Float16)a, (_Float16)b, (_Float16)c, (_Float16)d };
    return *reinterpret_cast<int2*>(&v);
}
__device__ __forceinline__ f16x8 frag_from(int a, int b, int c, int d) {
    i32x4 v = { a, b, c, d };
    return *reinterpret_cast<f16x8*>(&v);
}

__global__ __launch_bounds__(256) void hqae_kernel(
    const float* __restrict__ x,
    const float* __restrict__ qw,
    const float* __restrict__ W1, const float* __restrict__ b1,
    const float* __restrict__ W2, const float* __restrict__ b2,
    const float* __restrict__ W3, const float* __restrict__ b3,
    float* __restrict__ out)
{
    // ---- weights (block-shared, f16), one-time staging ----
    __shared__ alignas(16) f16x8 sW1h[16];   // [m][k0..7], k>=4 zero
    __shared__ alignas(16) f16x8 sW2h[64];   // (32,16): [row*2 + kblk]
    __shared__ alignas(16) f16x8 sW3h[64];   // (16,32): [row*4 + kblk]
    __shared__ alignas(16) float sb1[16];
    __shared__ alignas(16) float sb2[32];
    __shared__ alignas(16) float sb3[16];
    __shared__ float scw[4], ssw[4];

    const int tid = threadIdx.x;
    _Float16* w1p = (_Float16*)sW1h;
    _Float16* w2p = (_Float16*)sW2h;
    _Float16* w3p = (_Float16*)sW3h;
    for (int t = tid; t < 512; t += 256) {
        w2p[t] = (_Float16)W2[t];
        w3p[t] = (_Float16)W3[t];
    }
    if (tid < 128) w1p[tid] = ((tid & 7) < 4) ? (_Float16)W1[(tid >> 3) * 4 + (tid & 7)]
                                              : (_Float16)0.f;
    if (tid < 16) { sb1[tid] = b1[tid]; sb3[tid] = b3[tid]; }
    if (tid < 32) sb2[tid] = b2[tid];
    if (tid < 4)  { float a = qw[2 * tid]; scw[tid] = __cosf(a); ssw[tid] = __sinf(a); }
    __syncthreads();

    const int wv   = tid >> 6;
    const int lane = tid & 63;
    const int g    = lane >> 4;
    const int ln15 = lane & 15;

    // ---- hoisted weight fragments & biases ----
    f16x8 aW1   = sW1h[ln15];
    f32x4 bias1 = ((const f32x4*)sb1)[g];
    const int gh = g & 1;
    f16x8 aW2_0 = sW2h[(0 * 16 + ln15) * 2 + gh];     // rows 0..15
    f16x8 aW2_1 = sW2h[(1 * 16 + ln15) * 2 + gh];     // rows 16..31
    f32x4 bias2_0 = ((const f32x4*)sb2)[g];
    f32x4 bias2_1 = ((const f32x4*)sb2)[4 + g];
    f16x8 aW3   = sW3h[ln15 * 4 + g];                 // W3 row ln15, k=g*8..+7
    f32x4 bias3 = ((const f32x4*)sb3)[g];

    const float kq0 = scw[0], kq1 = scw[1], kq2 = scw[2], kq3 = scw[3];
    const float lq0 = ssw[0], lq1 = ssw[1], lq2 = ssw[2], lq3 = ssw[3];

    // shuffle source lanes (st-invariant)
    const int sA = ((g & 1) << 5) + ln15;
    const int sB = sA + 16;

    const int stride = gridDim.x;                     // blocks per pass

    // ---- prefetch pipeline over TPB tiles ----
    f32x4 cur0, cur1, cur2, cur3;
    {
        const int base = (blockIdx.x) * 256 + wv * 64;
        const f32x4* xin = reinterpret_cast<const f32x4*>(x + (size_t)(base + lane) * 16);
        cur0 = xin[0]; cur1 = xin[1]; cur2 = xin[2]; cur3 = xin[3];
    }

#pragma unroll
    for (int k = 0; k < TPB; ++k) {
        const int base = (blockIdx.x + k * stride) * 256 + wv * 64;

        f32x4 nxt0, nxt1, nxt2, nxt3;
        if (k + 1 < TPB) {
            const int nbase = (blockIdx.x + (k + 1) * stride) * 256 + wv * 64;
            const f32x4* xin = reinterpret_cast<const f32x4*>(x + (size_t)(nbase + lane) * 16);
            nxt0 = xin[0]; nxt1 = xin[1]; nxt2 = xin[2]; nxt3 = xin[3];
        }

        // ---------------- encoder (analytic), lane = sample ----------------
        int2 dz;
        {
            const float PI4 = 0.78539816339744831f;   // angle = mean*pi = sum*pi/4
            float t0 = (cur0[0] + cur0[1] + cur0[2] + cur0[3]) * PI4;
            float t1 = (cur1[0] + cur1[1] + cur1[2] + cur1[3]) * PI4;
            float t2 = (cur2[0] + cur2[1] + cur2[2] + cur2[3]) * PI4;
            float t3 = (cur3[0] + cur3[1] + cur3[2] + cur3[3]) * PI4;
            float C0 = __cosf(t0), S0 = __sinf(t0);
            float C1 = __cosf(t1), S1 = __sinf(t1);
            float C2 = __cosf(t2), S2 = __sinf(t2);
            float C3 = __cosf(t3), S3 = __sinf(t3);
            float C01 = C0 * C1, C012 = C01 * C2, C0123 = C012 * C3;
            float z0 = kq0 * C0    - lq0 * (S0 * S1);
            float z1 = kq1 * C01   - lq1 * (S1 * S2);
            float z2 = kq2 * C012  - lq2 * (S2 * S3);
            float z3 = kq3 * C0123 - lq3 * S3;
            dz = pack4(z0, z1, z2, z3);
        }

#pragma unroll
        for (int st = 0; st < 4; ++st) {
            // ---- layer 1: H1 = W1 . Z  (K=4 zero-padded) ----
            int src = st * 16 + ln15;
            int zlo = __shfl(dz.x, src), zhi = __shfl(dz.y, src);
            f16x8 bf1 = (g == 0) ? frag_from(zlo, zhi, 0, 0) : (f16x8)0;
            f32x4 d1 = __builtin_amdgcn_mfma_f32_16x16x32_f16(aW1, bf1, bias1, 0, 0, 0);
            int2 h1 = pack4(fmaxf(d1[0], 0.f), fmaxf(d1[1], 0.f),
                            fmaxf(d1[2], 0.f), fmaxf(d1[3], 0.f));

            // ---- layer 2: H2 = W2 . H1  (K=16: k-blocks 0,1) ----
            int b0 = __shfl(h1.x, sA), b1v = __shfl(h1.y, sA);
            int b2v = __shfl(h1.x, sB), b3v = __shfl(h1.y, sB);
            f16x8 bf2 = (g < 2) ? frag_from(b0, b1v, b2v, b3v) : (f16x8)0;
            f32x4 d2a = __builtin_amdgcn_mfma_f32_16x16x32_f16(aW2_0, bf2, bias2_0, 0, 0, 0);
            f32x4 d2b = __builtin_amdgcn_mfma_f32_16x16x32_f16(aW2_1, bf2, bias2_1, 0, 0, 0);
            int2 h2a = pack4(fmaxf(d2a[0], 0.f), fmaxf(d2a[1], 0.f),
                             fmaxf(d2a[2], 0.f), fmaxf(d2a[3], 0.f));
            int2 h2b = pack4(fmaxf(d2b[0], 0.f), fmaxf(d2b[1], 0.f),
                             fmaxf(d2b[2], 0.f), fmaxf(d2b[3], 0.f));

            // ---- layer 3: O = W3 . H2  (K=32 full) ----
            int a0 = __shfl(h2a.x, sA), a1 = __shfl(h2a.y, sA);
            int a2 = __shfl(h2a.x, sB), a3 = __shfl(h2a.y, sB);
            int c0 = __shfl(h2b.x, sA), c1 = __shfl(h2b.y, sA);
            int c2 = __shfl(h2b.x, sB), c3 = __shfl(h2b.y, sB);
            f16x8 bf3 = (g < 2) ? frag_from(a0, a1, a2, a3)
                                : frag_from(c0, c1, c2, c3);
            f32x4 d3 = __builtin_amdgcn_mfma_f32_16x16x32_f16(aW3, bf3, bias3, 0, 0, 0);

            // D[row=feature g*4+r][col=sample ln15] -> one 16B nt store/lane
            f32x4* op = reinterpret_cast<f32x4*>(out + (size_t)(base + st * 16 + ln15) * 16 + g * 4);
            __builtin_nontemporal_store(d3, op);
        }

        cur0 = nxt0; cur1 = nxt1; cur2 = nxt2; cur3 = nxt3;
    }
}

extern "C" void kernel_launch(void* const* d_in, const int* in_sizes, int n_in,
                              void* d_out, int out_size, void* d_ws, size_t ws_size,
                              hipStream_t stream) {
    const float* x  = (const float*)d_in[0];
    const float* qw = (const float*)d_in[1];
    const float* W1 = (const float*)d_in[2];
    const float* b1 = (const float*)d_in[3];
    const float* W2 = (const float*)d_in[4];
    const float* b2 = (const float*)d_in[5];
    const float* W3 = (const float*)d_in[6];
    const float* b3 = (const float*)d_in[7];
    float* out = (float*)d_out;

    const int B = in_sizes[0] / 16;              // 1048576
    const int grid = B / (256 * TPB);            // 1024 blocks
    hqae_kernel<<<grid, 256, 0, stream>>>(x, qw, W1, b1, W2, b2, W3, b3, out);
}

// Round 11
// 27.022 us; speedup vs baseline: 1.0338x; 1.0338x over previous
//
#include <hip/hip_runtime.h>

// HybridQAE: analytic encoder (Heisenberg-reduced: RZ drops out, CNOT+RY ->
// products of per-qubit cos/sin) + MFMA MLP 4->16->32->16 (16x16x32_f16,
// fp32 accum). One wave = 64 samples (lane = sample). All inter-layer
// fragment transposes via ds_bpermute (__shfl) -- zero LDS scratch, zero
// bank conflicts, no barriers. L3 unswapped so D = [feature][sample] and
// each lane stores one contiguous 16B vector (nontemporal).
// [r10 post-mortem] Best measured config (26.8us, r7). Grid-stride+prefetch
// (r10) and multi-tile (r5) both regressed: at 4096 blocks TLP already hides
// HBM latency; kernel sits at mixed-stream BW (~5 TB/s combined).

typedef _Float16 f16x8 __attribute__((ext_vector_type(8)));
typedef _Float16 f16x4 __attribute__((ext_vector_type(4)));
typedef float    f32x4 __attribute__((ext_vector_type(4)));
typedef int      i32x4 __attribute__((ext_vector_type(4)));

__device__ __forceinline__ int2 pack4(float a, float b, float c, float d) {
    f16x4 v = { (_Float16)a, (_Float16)b, (_Float16)c, (_Float16)d };
    return *reinterpret_cast<int2*>(&v);
}
__device__ __forceinline__ f16x8 frag_from(int a, int b, int c, int d) {
    i32x4 v = { a, b, c, d };
    return *reinterpret_cast<f16x8*>(&v);
}

__global__ __launch_bounds__(256) void hqae_kernel(
    const float* __restrict__ x,
    const float* __restrict__ qw,
    const float* __restrict__ W1, const float* __restrict__ b1,
    const float* __restrict__ W2, const float* __restrict__ b2,
    const float* __restrict__ W3, const float* __restrict__ b3,
    float* __restrict__ out)
{
    // ---- weights (block-shared, f16), one-time staging ----
    __shared__ alignas(16) f16x8 sW1h[16];   // [m][k0..7], k>=4 zero
    __shared__ alignas(16) f16x8 sW2h[64];   // (32,16): [row*2 + kblk]
    __shared__ alignas(16) f16x8 sW3h[64];   // (16,32): [row*4 + kblk]
    __shared__ alignas(16) float sb1[16];
    __shared__ alignas(16) float sb2[32];
    __shared__ alignas(16) float sb3[16];
    __shared__ float scw[4], ssw[4];

    const int tid = threadIdx.x;
    _Float16* w1p = (_Float16*)sW1h;
    _Float16* w2p = (_Float16*)sW2h;
    _Float16* w3p = (_Float16*)sW3h;
    for (int t = tid; t < 512; t += 256) {
        w2p[t] = (_Float16)W2[t];
        w3p[t] = (_Float16)W3[t];
    }
    if (tid < 128) w1p[tid] = ((tid & 7) < 4) ? (_Float16)W1[(tid >> 3) * 4 + (tid & 7)]
                                              : (_Float16)0.f;
    if (tid < 16) { sb1[tid] = b1[tid]; sb3[tid] = b3[tid]; }
    if (tid < 32) sb2[tid] = b2[tid];
    if (tid < 4)  { float a = qw[2 * tid]; scw[tid] = __cosf(a); ssw[tid] = __sinf(a); }
    __syncthreads();

    const int wv   = tid >> 6;
    const int lane = tid & 63;
    const int g    = lane >> 4;
    const int ln15 = lane & 15;
    const int base = blockIdx.x * 256 + wv * 64;

    // ---------------- encoder (analytic), lane = sample ----------------
    int2 dz;
    {
        const float4* xin = reinterpret_cast<const float4*>(x + (size_t)(base + lane) * 16);
        float4 a0 = xin[0], a1 = xin[1], a2 = xin[2], a3 = xin[3];
        const float PI4 = 0.78539816339744831f;   // angle = mean*pi = sum*pi/4
        float t0 = (a0.x + a0.y + a0.z + a0.w) * PI4;
        float t1 = (a1.x + a1.y + a1.z + a1.w) * PI4;
        float t2 = (a2.x + a2.y + a2.z + a2.w) * PI4;
        float t3 = (a3.x + a3.y + a3.z + a3.w) * PI4;
        float C0 = __cosf(t0), S0 = __sinf(t0);
        float C1 = __cosf(t1), S1 = __sinf(t1);
        float C2 = __cosf(t2), S2 = __sinf(t2);
        float C3 = __cosf(t3), S3 = __sinf(t3);
        float C01 = C0 * C1, C012 = C01 * C2, C0123 = C012 * C3;
        float z0 = scw[0] * C0    - ssw[0] * (S0 * S1);
        float z1 = scw[1] * C01   - ssw[1] * (S1 * S2);
        float z2 = scw[2] * C012  - ssw[2] * (S2 * S3);
        float z3 = scw[3] * C0123 - ssw[3] * S3;
        dz = pack4(z0, z1, z2, z3);
    }

    // ---------------- hoisted weight fragments & biases ----------------
    f16x8 aW1   = sW1h[ln15];
    f32x4 bias1 = ((const f32x4*)sb1)[g];
    const int gh = g & 1;
    f16x8 aW2_0 = sW2h[(0 * 16 + ln15) * 2 + gh];     // rows 0..15
    f16x8 aW2_1 = sW2h[(1 * 16 + ln15) * 2 + gh];     // rows 16..31
    f32x4 bias2_0 = ((const f32x4*)sb2)[g];
    f32x4 bias2_1 = ((const f32x4*)sb2)[4 + g];
    f16x8 aW3   = sW3h[ln15 * 4 + g];                 // W3 row ln15, k=g*8..+7
    f32x4 bias3 = ((const f32x4*)sb3)[g];

    // shuffle source lanes (st-invariant): feature-pair sources for the
    // [4-rows-per-group]->[8-k-per-group] fragment regroupings
    const int sA = ((g & 1) << 5) + ln15;   // lanes holding features blk*8+0..3
    const int sB = sA + 16;                 // lanes holding features blk*8+4..7

#pragma unroll
    for (int st = 0; st < 4; ++st) {
        // ---- layer 1: H1 = W1 . Z  (K=4 zero-padded) ----
        int src = st * 16 + ln15;
        int zlo = __shfl(dz.x, src), zhi = __shfl(dz.y, src);
        f16x8 bf1 = (g == 0) ? frag_from(zlo, zhi, 0, 0) : (f16x8)0;
        f32x4 d1 = __builtin_amdgcn_mfma_f32_16x16x32_f16(aW1, bf1, bias1, 0, 0, 0);
        int2 h1 = pack4(fmaxf(d1[0], 0.f), fmaxf(d1[1], 0.f),
                        fmaxf(d1[2], 0.f), fmaxf(d1[3], 0.f));

        // ---- layer 2: H2 = W2 . H1  (K=16: k-blocks 0,1) ----
        int b0 = __shfl(h1.x, sA), b1v = __shfl(h1.y, sA);
        int b2v = __shfl(h1.x, sB), b3v = __shfl(h1.y, sB);
        f16x8 bf2 = (g < 2) ? frag_from(b0, b1v, b2v, b3v) : (f16x8)0;
        f32x4 d2a = __builtin_amdgcn_mfma_f32_16x16x32_f16(aW2_0, bf2, bias2_0, 0, 0, 0);
        f32x4 d2b = __builtin_amdgcn_mfma_f32_16x16x32_f16(aW2_1, bf2, bias2_1, 0, 0, 0);
        int2 h2a = pack4(fmaxf(d2a[0], 0.f), fmaxf(d2a[1], 0.f),
                         fmaxf(d2a[2], 0.f), fmaxf(d2a[3], 0.f));   // features 0..15
        int2 h2b = pack4(fmaxf(d2b[0], 0.f), fmaxf(d2b[1], 0.f),
                         fmaxf(d2b[2], 0.f), fmaxf(d2b[3], 0.f));   // features 16..31

        // ---- layer 3: O = W3 . H2  (K=32 full) ----
        int a0 = __shfl(h2a.x, sA), a1 = __shfl(h2a.y, sA);
        int a2 = __shfl(h2a.x, sB), a3 = __shfl(h2a.y, sB);
        int c0 = __shfl(h2b.x, sA), c1 = __shfl(h2b.y, sA);
        int c2 = __shfl(h2b.x, sB), c3 = __shfl(h2b.y, sB);
        f16x8 bf3 = (g < 2) ? frag_from(a0, a1, a2, a3)
                            : frag_from(c0, c1, c2, c3);
        f32x4 d3 = __builtin_amdgcn_mfma_f32_16x16x32_f16(aW3, bf3, bias3, 0, 0, 0);

        // D[row=out-feature g*4+r][col=sample ln15] -> one 16B store per lane
        f32x4* op = reinterpret_cast<f32x4*>(out + (size_t)(base + st * 16 + ln15) * 16 + g * 4);
        __builtin_nontemporal_store(d3, op);
    }
}

extern "C" void kernel_launch(void* const* d_in, const int* in_sizes, int n_in,
                              void* d_out, int out_size, void* d_ws, size_t ws_size,
                              hipStream_t stream) {
    const float* x  = (const float*)d_in[0];
    const float* qw = (const float*)d_in[1];
    const float* W1 = (const float*)d_in[2];
    const float* b1 = (const float*)d_in[3];
    const float* W2 = (const float*)d_in[4];
    const float* b2 = (const float*)d_in[5];
    const float* W3 = (const float*)d_in[6];
    const float* b3 = (const float*)d_in[7];
    float* out = (float*)d_out;

    const int B = in_sizes[0] / 16;              // 1048576
    hqae_kernel<<<B / 256, 256, 0, stream>>>(x, qw, W1, b1, W2, b2, W3, b3, out);
}